// Round 1
// baseline (299.580 us; speedup 1.0000x reference)
//
#include <hip/hip_runtime.h>
#include <hip/hip_bf16.h>
#include <math.h>

// Shapes: B=1, M=2, L=256, D=256, D2=512, S=128.
// Row convention: r = t*512 + (m*256 + l), t in {0(x),1(mouth)}.

#define D_   256
#define D2_  512
#define S_   128
#define ROWS 512      // m*l rows per tensor

__device__ __forceinline__ float silu_f(float v) {
    return v / (1.f + __expf(-v));
}

// ---------------- rmsnorm: 1024 blocks x 256 threads ----------------
__global__ void rmsnorm_k(const float* __restrict__ x, const float* __restrict__ mouth,
                          const float* __restrict__ w, float* __restrict__ out) {
    int r = blockIdx.x;               // 0..1023
    int t = threadIdx.x;              // 0..255
    const float* src = (r < ROWS) ? (x + (size_t)r * D_) : (mouth + (size_t)(r - ROWS) * D_);
    float v = src[t];
    __shared__ float red[D_];
    red[t] = v * v;
    __syncthreads();
    for (int s = 128; s > 0; s >>= 1) {
        if (t < s) red[t] += red[t + s];
        __syncthreads();
    }
    float rms = sqrtf(red[0] + 1e-5f);
    out[(size_t)r * D_ + t] = v / rms * w[t];
}

// ---------------- generic linear: out[r][c] = act(in[r]·W[c] + b[c]) ----------------
// ACT: 0 none, 1 silu, 2 softplus.  Block = C threads, each block does TR rows.
template<int ACT, int TR>
__global__ void linear_k(const float* __restrict__ in, const float* __restrict__ W,
                         const float* __restrict__ bias, float* __restrict__ out,
                         int K, int C) {
    int c = threadIdx.x;
    int r0 = blockIdx.x * TR;
    float acc[TR];
#pragma unroll
    for (int r = 0; r < TR; ++r) acc[r] = 0.f;
    const float* Wr = W + (size_t)c * K;
    for (int k = 0; k < K; k += 4) {
        float4 w4 = *reinterpret_cast<const float4*>(Wr + k);
#pragma unroll
        for (int r = 0; r < TR; ++r) {
            float4 i4 = *reinterpret_cast<const float4*>(in + (size_t)(r0 + r) * K + k);
            acc[r] = fmaf(i4.x, w4.x, acc[r]);
            acc[r] = fmaf(i4.y, w4.y, acc[r]);
            acc[r] = fmaf(i4.z, w4.z, acc[r]);
            acc[r] = fmaf(i4.w, w4.w, acc[r]);
        }
    }
    float b = bias[c];
#pragma unroll
    for (int r = 0; r < TR; ++r) {
        float v = acc[r] + b;
        if (ACT == 1) v = silu_f(v);
        else if (ACT == 2) v = fmaxf(v, 0.f) + log1pf(__expf(-fabsf(v)));  // softplus, stable
        out[(size_t)(r0 + r) * C + c] = v;
    }
}

// ---------------- 3x3 SAME conv over (C=2, H=256, W=512), + bias + silu ----------------
// xp layout: [(t*2+i)*256 + l][w]  (i = channel m)
__global__ void conv_silu_k(const float* __restrict__ xp, const float* __restrict__ cW,
                            const float* __restrict__ cb, float* __restrict__ xc) {
    int idx = blockIdx.x * blockDim.x + threadIdx.x;   // < 2*2*256*512
    int w = idx & 511;
    int l = (idx >> 9) & 255;
    int o = (idx >> 17) & 1;
    int t = idx >> 18;
    float acc = cb[o];
#pragma unroll
    for (int i = 0; i < 2; ++i) {
        const float* base = xp + (size_t)((t * 2 + i) * 256) * 512;
#pragma unroll
        for (int dh = -1; dh <= 1; ++dh) {
            int ll = l + dh;
            if (ll < 0 || ll > 255) continue;
#pragma unroll
            for (int dw = -1; dw <= 1; ++dw) {
                int ww = w + dw;
                if (ww < 0 || ww > 511) continue;
                acc += base[(size_t)ll * 512 + ww] * cW[((o * 2 + i) * 3 + (dh + 1)) * 3 + (dw + 1)];
            }
        }
    }
    xc[idx] = silu_f(acc);
}

// ---------------- fused SSM + silu + combine with res ----------------
// Per row (m*256+l): comb[d] = (silu(ssm_x[d]) + silu(ssm_m[d])) * res[row][d]
// ssm[d] = sum_n Bm[n]*exp(delta[d]*A[d,n]) + xc[d]*delta[d]*sum_n Bm[n]^2
__global__ void ssm_combine_k(const float* __restrict__ xc, const float* __restrict__ delta,
                              const float* __restrict__ Bm, const float* __restrict__ A,
                              const float* __restrict__ res, float* __restrict__ comb) {
    int row = blockIdx.x;             // 0..511
    int d = threadIdx.x;              // 0..511
    __shared__ float bx[S_], bm[S_];
    __shared__ float s2[2];
    if (d < S_)            bx[d]        = Bm[(size_t)row * S_ + d];
    else if (d < 2 * S_)   bm[d - S_]   = Bm[(size_t)(ROWS + row) * S_ + (d - S_)];
    __syncthreads();
    if (d == 0)  { float s = 0.f; for (int n = 0; n < S_; ++n) s += bx[n] * bx[n]; s2[0] = s; }
    if (d == 64) { float s = 0.f; for (int n = 0; n < S_; ++n) s += bm[n] * bm[n]; s2[1] = s; }
    __syncthreads();
    float dx = delta[(size_t)row * D2_ + d];
    float dm = delta[(size_t)(ROWS + row) * D2_ + d];
    float xx = xc[(size_t)row * D2_ + d];
    float xm = xc[(size_t)(ROWS + row) * D2_ + d];
    const float* Ad = A + (size_t)d * S_;
    float accx = 0.f, accm = 0.f;
    for (int n = 0; n < S_; n += 4) {
        float4 a4 = *reinterpret_cast<const float4*>(Ad + n);
        accx += bx[n]     * __expf(dx * a4.x);
        accx += bx[n + 1] * __expf(dx * a4.y);
        accx += bx[n + 2] * __expf(dx * a4.z);
        accx += bx[n + 3] * __expf(dx * a4.w);
        accm += bm[n]     * __expf(dm * a4.x);
        accm += bm[n + 1] * __expf(dm * a4.y);
        accm += bm[n + 2] * __expf(dm * a4.z);
        accm += bm[n + 3] * __expf(dm * a4.w);
    }
    float sx = accx + xx * dx * s2[0];
    float sm = accm + xm * dm * s2[1];
    comb[(size_t)row * D2_ + d] = (silu_f(sx) + silu_f(sm)) * res[(size_t)row * D2_ + d];
}

extern "C" void kernel_launch(void* const* d_in, const int* in_sizes, int n_in,
                              void* d_out, int out_size, void* d_ws, size_t ws_size,
                              hipStream_t stream) {
    const float* x      = (const float*)d_in[0];
    const float* mouth  = (const float*)d_in[1];
    const float* norm_w = (const float*)d_in[2];
    const float* inp_W  = (const float*)d_in[3];
    const float* inp_b  = (const float*)d_in[4];
    const float* out_W  = (const float*)d_in[5];
    const float* out_b  = (const float*)d_in[6];
    const float* Dlin_W = (const float*)d_in[7];
    const float* Dlin_b = (const float*)d_in[8];
    const float* conv_W = (const float*)d_in[9];
    const float* conv_b = (const float*)d_in[10];
    const float* fc1_W  = (const float*)d_in[11];
    const float* fc1_b  = (const float*)d_in[12];
    const float* fc2_W  = (const float*)d_in[13];
    const float* fc2_b  = (const float*)d_in[14];
    const float* A      = (const float*)d_in[15];

    float* ws   = (float*)d_ws;
    float* xn   = ws;                       // 1024*256  = 262144
    float* xp   = xn + 1024 * 256;          // 1024*512  = 524288 (reused as delta after conv)
    float* xc   = xp + 1024 * 512;          // 1024*512  = 524288
    float* res  = xc + 1024 * 512;          // 512*512   = 262144
    float* comb = res + 512 * 512;          // 512*512   = 262144
    float* delta = xp;                      // alias: xp dead after conv
    float* Bmb   = xn;                      // alias: xn dead after Dlin; 1024*128 fits
    float* out   = (float*)d_out;

    // 1) rmsnorm of x (rows 0..511) and mouth (rows 512..1023)
    rmsnorm_k<<<1024, 256, 0, stream>>>(x, mouth, norm_w, xn);
    // 2) xp = xn @ inp_W^T + inp_b           (1024 x 512, K=256)
    linear_k<0, 8><<<128, 512, 0, stream>>>(xn, inp_W, inp_b, xp, 256, 512);
    // 3) res = silu(xn[x-half] @ Dlin_W^T + Dlin_b)   (512 x 512, K=256)
    linear_k<1, 8><<<64, 512, 0, stream>>>(xn, Dlin_W, Dlin_b, res, 256, 512);
    // 4) xc = silu(conv3x3(xp) + cb)
    conv_silu_k<<<2048, 256, 0, stream>>>(xp, conv_W, conv_b, xc);
    // 5) delta = softplus(xc @ fc1_W^T + fc1_b)   (1024 x 512, K=512)  [writes over xp]
    linear_k<2, 8><<<128, 512, 0, stream>>>(xc, fc1_W, fc1_b, delta, 512, 512);
    // 6) Bm = xc @ fc2_W^T + fc2_b           (1024 x 128, K=512)  [writes over xn]
    linear_k<0, 8><<<128, 128, 0, stream>>>(xc, fc2_W, fc2_b, Bmb, 512, 128);
    // 7) comb = (silu(ssm_x) + silu(ssm_m)) * res    (512 x 512)
    ssm_combine_k<<<512, 512, 0, stream>>>(xc, delta, Bmb, A, res, comb);
    // 8) out = comb @ out_W^T + out_b        (512 x 256, K=512)
    linear_k<0, 8><<<64, 256, 0, stream>>>(comb, out_W, out_b, out, 512, 256);
}

// Round 3
// 238.873 us; speedup vs baseline: 1.2541x; 1.2541x over previous
//
#include <hip/hip_runtime.h>
#include <hip/hip_bf16.h>
#include <math.h>

// Shapes: B=1, M=2, L=256, D=256, D2=512, S=128.
// Row convention: r = t*512 + (m*256 + l), t in {0(x),1(mouth)}.

#define D_   256
#define D2_  512
#define S_   128
#define ROWS 512      // m*l rows per tensor

__device__ __forceinline__ float silu_f(float v) {
    return v / (1.f + __expf(-v));
}
__device__ __forceinline__ float softplus_f(float v) {
    return fmaxf(v, 0.f) + log1pf(__expf(-fabsf(v)));
}

// ---------------- rmsnorm: 1024 blocks x 256 threads ----------------
__global__ void rmsnorm_k(const float* __restrict__ x, const float* __restrict__ mouth,
                          const float* __restrict__ w, float* __restrict__ out) {
    int r = blockIdx.x;               // 0..1023
    int t = threadIdx.x;              // 0..255
    const float* src = (r < ROWS) ? (x + (size_t)r * D_) : (mouth + (size_t)(r - ROWS) * D_);
    float v = src[t];
    __shared__ float red[D_];
    red[t] = v * v;
    __syncthreads();
    for (int s = 128; s > 0; s >>= 1) {
        if (t < s) red[t] += red[t + s];
        __syncthreads();
    }
    float rms = sqrtf(red[0] + 1e-5f);
    out[(size_t)r * D_ + t] = v / rms * w[t];
}

// ---------------- tiled GEMM: out[r][c] = act(in[r]·W[c] + b[c]) ----------------
// 64x64 tile per block, 512 threads (8 waves). K-major transposed LDS staging,
// register double-buffered prefetch, one __syncthreads per 16-wide K chunk.
// Per thread: 4 rows x 2 cols.  Requires M%64==0, C%64==0, K%16==0.
template<int ACT>
__global__ __launch_bounds__(512)
void gemm_k(const float* __restrict__ in, const float* __restrict__ W,
            const float* __restrict__ bias, float* __restrict__ out,
            int K, int ldo) {
    __shared__ float As[2][16][64];
    __shared__ float Ws[2][16][64];
    const int t  = threadIdx.x;
    const int r0 = blockIdx.x * 64, c0 = blockIdx.y * 64;
    // staging: each thread loads one float2 from A and one from W per chunk
    const int srow = t >> 3;          // 0..63
    const int sk   = (t & 7) * 2;     // 0,2,..,14
    // compute: 4 rows x 2 cols per thread
    const int tr = (t >> 5) * 4;      // 0..60
    const int tc = (t & 31) * 2;      // 0..62
    const float* Ap = in + (size_t)(r0 + srow) * K + sk;
    const float* Wp = W  + (size_t)(c0 + srow) * K + sk;
    float2 areg = *(const float2*)Ap;
    float2 wreg = *(const float2*)Wp;
    float acc[4][2] = {};
    const int nch = K >> 4;
    for (int ch = 0; ch < nch; ++ch) {
        const int p = ch & 1;
        As[p][sk    ][srow] = areg.x;
        As[p][sk + 1][srow] = areg.y;
        Ws[p][sk    ][srow] = wreg.x;
        Ws[p][sk + 1][srow] = wreg.y;
        __syncthreads();
        if (ch + 1 < nch) {
            areg = *(const float2*)(Ap + (size_t)(ch + 1) * 16);
            wreg = *(const float2*)(Wp + (size_t)(ch + 1) * 16);
        }
#pragma unroll
        for (int kk = 0; kk < 16; ++kk) {
            float4 a4 = *(const float4*)&As[p][kk][tr];
            float2 w2 = *(const float2*)&Ws[p][kk][tc];
            acc[0][0] = fmaf(a4.x, w2.x, acc[0][0]);
            acc[0][1] = fmaf(a4.x, w2.y, acc[0][1]);
            acc[1][0] = fmaf(a4.y, w2.x, acc[1][0]);
            acc[1][1] = fmaf(a4.y, w2.y, acc[1][1]);
            acc[2][0] = fmaf(a4.z, w2.x, acc[2][0]);
            acc[2][1] = fmaf(a4.z, w2.y, acc[2][1]);
            acc[3][0] = fmaf(a4.w, w2.x, acc[3][0]);
            acc[3][1] = fmaf(a4.w, w2.y, acc[3][1]);
        }
        __syncthreads();
    }
    float2 bv = *(const float2*)(bias + c0 + tc);
#pragma unroll
    for (int i = 0; i < 4; ++i) {
        float vx = acc[i][0] + bv.x;
        float vy = acc[i][1] + bv.y;
        if (ACT == 1) { vx = silu_f(vx); vy = silu_f(vy); }
        else if (ACT == 2) { vx = softplus_f(vx); vy = softplus_f(vy); }
        float2 v = make_float2(vx, vy);
        *(float2*)(out + (size_t)(r0 + tr + i) * ldo + c0 + tc) = v;
    }
}

// ---------------- 3x3 SAME conv over (C=2, H=256, W=512), + bias + silu ----------------
// xp layout: [(t*2+i)*256 + l][w]  (i = channel m)
__global__ void conv_silu_k(const float* __restrict__ xp, const float* __restrict__ cW,
                            const float* __restrict__ cb, float* __restrict__ xc) {
    int idx = blockIdx.x * blockDim.x + threadIdx.x;   // < 2*2*256*512
    int w = idx & 511;
    int l = (idx >> 9) & 255;
    int o = (idx >> 17) & 1;
    int t = idx >> 18;
    float acc = cb[o];
#pragma unroll
    for (int i = 0; i < 2; ++i) {
        const float* base = xp + (size_t)((t * 2 + i) * 256) * 512;
#pragma unroll
        for (int dh = -1; dh <= 1; ++dh) {
            int ll = l + dh;
            if (ll < 0 || ll > 255) continue;
#pragma unroll
            for (int dw = -1; dw <= 1; ++dw) {
                int ww = w + dw;
                if (ww < 0 || ww > 511) continue;
                acc += base[(size_t)ll * 512 + ww] * cW[((o * 2 + i) * 3 + (dh + 1)) * 3 + (dw + 1)];
            }
        }
    }
    xc[idx] = silu_f(acc);
}

// ---------------- fused SSM + silu + combine with res ----------------
// Per row (m*256+l): comb[d] = (silu(ssm_x[d]) + silu(ssm_m[d])) * res[row][d]
// ssm[d] = sum_n Bm[n]*exp(delta[d]*A[d,n]) + xc[d]*delta[d]*sum_n Bm[n]^2
__global__ void ssm_combine_k(const float* __restrict__ xc, const float* __restrict__ delta,
                              const float* __restrict__ Bm, const float* __restrict__ A,
                              const float* __restrict__ res, float* __restrict__ comb) {
    int row = blockIdx.x;             // 0..511
    int d = threadIdx.x;              // 0..511
    __shared__ float bx[S_], bm[S_];
    __shared__ float s2[2];
    if (d < S_)            bx[d]        = Bm[(size_t)row * S_ + d];
    else if (d < 2 * S_)   bm[d - S_]   = Bm[(size_t)(ROWS + row) * S_ + (d - S_)];
    __syncthreads();
    if (d == 0)  { float s = 0.f; for (int n = 0; n < S_; ++n) s += bx[n] * bx[n]; s2[0] = s; }
    if (d == 64) { float s = 0.f; for (int n = 0; n < S_; ++n) s += bm[n] * bm[n]; s2[1] = s; }
    __syncthreads();
    float dx = delta[(size_t)row * D2_ + d];
    float dm = delta[(size_t)(ROWS + row) * D2_ + d];
    float xx = xc[(size_t)row * D2_ + d];
    float xm = xc[(size_t)(ROWS + row) * D2_ + d];
    const float* Ad = A + (size_t)d * S_;
    float accx = 0.f, accm = 0.f;
    for (int n = 0; n < S_; n += 4) {
        float4 a4 = *reinterpret_cast<const float4*>(Ad + n);
        accx += bx[n]     * __expf(dx * a4.x);
        accx += bx[n + 1] * __expf(dx * a4.y);
        accx += bx[n + 2] * __expf(dx * a4.z);
        accx += bx[n + 3] * __expf(dx * a4.w);
        accm += bm[n]     * __expf(dm * a4.x);
        accm += bm[n + 1] * __expf(dm * a4.y);
        accm += bm[n + 2] * __expf(dm * a4.z);
        accm += bm[n + 3] * __expf(dm * a4.w);
    }
    float sx = accx + xx * dx * s2[0];
    float sm = accm + xm * dm * s2[1];
    comb[(size_t)row * D2_ + d] = (silu_f(sx) + silu_f(sm)) * res[(size_t)row * D2_ + d];
}

extern "C" void kernel_launch(void* const* d_in, const int* in_sizes, int n_in,
                              void* d_out, int out_size, void* d_ws, size_t ws_size,
                              hipStream_t stream) {
    const float* x      = (const float*)d_in[0];
    const float* mouth  = (const float*)d_in[1];
    const float* norm_w = (const float*)d_in[2];
    const float* inp_W  = (const float*)d_in[3];
    const float* inp_b  = (const float*)d_in[4];
    const float* out_W  = (const float*)d_in[5];
    const float* out_b  = (const float*)d_in[6];
    const float* Dlin_W = (const float*)d_in[7];
    const float* Dlin_b = (const float*)d_in[8];
    const float* conv_W = (const float*)d_in[9];
    const float* conv_b = (const float*)d_in[10];
    const float* fc1_W  = (const float*)d_in[11];
    const float* fc1_b  = (const float*)d_in[12];
    const float* fc2_W  = (const float*)d_in[13];
    const float* fc2_b  = (const float*)d_in[14];
    const float* A      = (const float*)d_in[15];

    float* ws   = (float*)d_ws;
    float* xn   = ws;                       // 1024*256  = 262144
    float* xp   = xn + 1024 * 256;          // 1024*512  = 524288 (reused as delta after conv)
    float* xc   = xp + 1024 * 512;          // 1024*512  = 524288
    float* res  = xc + 1024 * 512;          // 512*512   = 262144
    float* comb = res + 512 * 512;          // 512*512   = 262144
    float* delta = xp;                      // alias: xp dead after conv
    float* Bmb   = xn;                      // alias: xn dead after Dlin; 1024*128 fits
    float* out   = (float*)d_out;

    // 1) rmsnorm of x (rows 0..511) and mouth (rows 512..1023)
    rmsnorm_k<<<1024, 256, 0, stream>>>(x, mouth, norm_w, xn);
    // 2) xp = xn @ inp_W^T + inp_b           (1024 x 512, K=256)
    gemm_k<0><<<dim3(16, 8), 512, 0, stream>>>(xn, inp_W, inp_b, xp, 256, 512);
    // 3) res = silu(xn[x-half] @ Dlin_W^T + Dlin_b)   (512 x 512, K=256)
    gemm_k<1><<<dim3(8, 8), 512, 0, stream>>>(xn, Dlin_W, Dlin_b, res, 256, 512);
    // 4) xc = silu(conv3x3(xp) + cb)
    conv_silu_k<<<2048, 256, 0, stream>>>(xp, conv_W, conv_b, xc);
    // 5) delta = softplus(xc @ fc1_W^T + fc1_b)   (1024 x 512, K=512)  [writes over xp]
    gemm_k<2><<<dim3(16, 8), 512, 0, stream>>>(xc, fc1_W, fc1_b, delta, 512, 512);
    // 6) Bm = xc @ fc2_W^T + fc2_b           (1024 x 128, K=512)  [writes over xn]
    gemm_k<0><<<dim3(16, 2), 512, 0, stream>>>(xc, fc2_W, fc2_b, Bmb, 512, 128);
    // 7) comb = (silu(ssm_x) + silu(ssm_m)) * res    (512 x 512)
    ssm_combine_k<<<512, 512, 0, stream>>>(xc, delta, Bmb, A, res, comb);
    // 8) out = comb @ out_W^T + out_b        (512 x 256, K=512)
    gemm_k<0><<<dim3(8, 4), 512, 0, stream>>>(comb, out_W, out_b, out, 512, 256);
}

// Round 7
// 173.936 us; speedup vs baseline: 1.7224x; 1.3733x over previous
//
#include <hip/hip_runtime.h>
#include <hip/hip_bf16.h>
#include <math.h>

// Shapes: B=1, M=2, L=256, D=256, D2=512, S=128.
// Row convention: r = t*512 + (m*256 + l), t in {0(x),1(mouth)}.

#define D_   256
#define D2_  512
#define S_   128

__device__ __forceinline__ float silu_f(float v) {
    return v / (1.f + __expf(-v));
}
__device__ __forceinline__ float softplus_f(float v) {
    return fmaxf(v, 0.f) + log1pf(__expf(-fabsf(v)));
}

// ---- invr[r] = 1/sqrt(sum_k row[k]^2 + eps); rows 0..511 = x, 512..1023 = mouth ----
__global__ __launch_bounds__(256) void invrms_k(const float* __restrict__ x,
                                                const float* __restrict__ mouth,
                                                float* __restrict__ invr) {
    int wave = threadIdx.x >> 6;          // 0..3
    int lane = threadIdx.x & 63;
    int r = blockIdx.x * 4 + wave;        // 0..1023
    const float* src = (r < 512) ? (x + (size_t)r * D_) : (mouth + (size_t)(r - 512) * D_);
    float4 v = *(const float4*)(src + lane * 4);
    float s = v.x * v.x + v.y * v.y + v.z * v.z + v.w * v.w;
    for (int off = 32; off; off >>= 1) s += __shfl_xor(s, off);
    if (lane == 0) invr[r] = 1.f / sqrtf(s + 1e-5f);
}

// ---- dual-output tiled GEMM: tile 32(M) x 64(N), 256 threads, KC=32 ----
// blocks [0,n1): O1 = act1(A@W1^T + b1); blocks [n1,..): O2 = act2(A@W2^T + b2).
// NORM: A[r][k] scaled by invr[r]*nw[k] during staging (fused rmsnorm).
// A rows >= 512 come from A1 (A1 = mouth, or A0+512*K for contiguous buffers).
// k-major LDS with pad (36/68) -> <=4-way write conflicts, clean vector reads.
// One __syncthreads per chunk (store ch -> barrier -> prefetch ch+1 -> compute ch);
// safe because compute(ch) precedes barrier(ch+1), and stores to buffer p at
// iter ch+2 happen only after barrier(ch+1).
template<bool NORM, int ACT1, int ACT2>
__global__ __launch_bounds__(256) void gemm_dual_k(
        const float* __restrict__ A0, const float* __restrict__ A1,
        const float* __restrict__ nw, const float* __restrict__ invr,
        const float* __restrict__ W1, const float* __restrict__ bias1,
        float* __restrict__ O1, int nct1, int ldo1, int n1,
        const float* __restrict__ W2, const float* __restrict__ bias2,
        float* __restrict__ O2, int nct2, int ldo2, int K) {
    __shared__ float As[2][32][36];
    __shared__ float Ws[2][32][68];
    const int b = blockIdx.x;
    const float *W, *bias; float* O; int ldo, act, rt, ct;
    if (b < n1) { W = W1; bias = bias1; O = O1; ldo = ldo1; act = ACT1; rt = b / nct1; ct = b % nct1; }
    else { int bb = b - n1; W = W2; bias = bias2; O = O2; ldo = ldo2; act = ACT2; rt = bb / nct2; ct = bb % nct2; }
    const int r0 = rt * 32, c0 = ct * 64;
    const int t = threadIdx.x;
    const int sr = t >> 3;                // 0..31
    const int sk = (t & 7) << 2;          // 0..28
    const int rowA = r0 + sr;
    const float* Abase = ((rowA < 512) ? (A0 + (size_t)rowA * K)
                                       : (A1 + (size_t)(rowA - 512) * K)) + sk;
    const float* W1base = W + (size_t)(c0 + sr) * K + sk;
    const float* W2base = W + (size_t)(c0 + 32 + sr) * K + sk;
    const float ascale = NORM ? invr[rowA] : 0.f;
    float4 areg = *(const float4*)Abase;
    float4 w1reg = *(const float4*)W1base;
    float4 w2reg = *(const float4*)W2base;
    float4 nwreg = NORM ? *(const float4*)(nw + sk) : make_float4(0.f, 0.f, 0.f, 0.f);
    const int tr = (t >> 5) << 2;         // 0..28
    const int tc = (t & 31) << 1;         // 0..62
    float acc[4][2] = {};
    const int nch = K >> 5;
    for (int ch = 0; ch < nch; ++ch) {
        const int p = ch & 1;
        float4 a = areg;
        if (NORM) {
            a.x *= ascale * nwreg.x; a.y *= ascale * nwreg.y;
            a.z *= ascale * nwreg.z; a.w *= ascale * nwreg.w;
        }
        As[p][sk + 0][sr] = a.x;  As[p][sk + 1][sr] = a.y;
        As[p][sk + 2][sr] = a.z;  As[p][sk + 3][sr] = a.w;
        Ws[p][sk + 0][sr] = w1reg.x;  Ws[p][sk + 1][sr] = w1reg.y;
        Ws[p][sk + 2][sr] = w1reg.z;  Ws[p][sk + 3][sr] = w1reg.w;
        Ws[p][sk + 0][sr + 32] = w2reg.x;  Ws[p][sk + 1][sr + 32] = w2reg.y;
        Ws[p][sk + 2][sr + 32] = w2reg.z;  Ws[p][sk + 3][sr + 32] = w2reg.w;
        __syncthreads();
        if (ch + 1 < nch) {
            const int ko = (ch + 1) << 5;
            areg  = *(const float4*)(Abase + ko);
            w1reg = *(const float4*)(W1base + ko);
            w2reg = *(const float4*)(W2base + ko);
            if (NORM) nwreg = *(const float4*)(nw + ko + sk);
        }
#pragma unroll
        for (int kk = 0; kk < 32; ++kk) {
            const float4 a4 = *(const float4*)&As[p][kk][tr];
            const float2 w2 = *(const float2*)&Ws[p][kk][tc];
            acc[0][0] = fmaf(a4.x, w2.x, acc[0][0]); acc[0][1] = fmaf(a4.x, w2.y, acc[0][1]);
            acc[1][0] = fmaf(a4.y, w2.x, acc[1][0]); acc[1][1] = fmaf(a4.y, w2.y, acc[1][1]);
            acc[2][0] = fmaf(a4.z, w2.x, acc[2][0]); acc[2][1] = fmaf(a4.z, w2.y, acc[2][1]);
            acc[3][0] = fmaf(a4.w, w2.x, acc[3][0]); acc[3][1] = fmaf(a4.w, w2.y, acc[3][1]);
        }
        // no trailing barrier: next iter stores to the other buffer (safe)
    }
    const float2 bv = *(const float2*)(bias + c0 + tc);
#pragma unroll
    for (int i = 0; i < 4; ++i) {
        float vx = acc[i][0] + bv.x, vy = acc[i][1] + bv.y;
        if (act == 1)      { vx = silu_f(vx);     vy = silu_f(vy); }
        else if (act == 2) { vx = softplus_f(vx); vy = softplus_f(vy); }
        *(float2*)(O + (size_t)(r0 + tr + i) * ldo + c0 + tc) = make_float2(vx, vy);
    }
}

// ---- 3x3 SAME conv over (C=2, H=256, W=512), + bias + silu ----
__global__ void conv_silu_k(const float* __restrict__ xp, const float* __restrict__ cW,
                            const float* __restrict__ cb, float* __restrict__ xc) {
    int idx = blockIdx.x * blockDim.x + threadIdx.x;   // < 2*2*256*512
    int w = idx & 511;
    int l = (idx >> 9) & 255;
    int o = (idx >> 17) & 1;
    int t = idx >> 18;
    float acc = cb[o];
#pragma unroll
    for (int i = 0; i < 2; ++i) {
        const float* base = xp + (size_t)((t * 2 + i) * 256) * 512;
#pragma unroll
        for (int dh = -1; dh <= 1; ++dh) {
            int ll = l + dh;
            if (ll < 0 || ll > 255) continue;
#pragma unroll
            for (int dw = -1; dw <= 1; ++dw) {
                int ww = w + dw;
                if (ww < 0 || ww > 511) continue;
                acc += base[(size_t)ll * 512 + ww] * cW[((o * 2 + i) * 3 + (dh + 1)) * 3 + (dw + 1)];
            }
        }
    }
    xc[idx] = silu_f(acc);
}

// ---- fused SSM + silu + combine with res ----
// ssm[d] = sum_n Bm[n]*exp(delta[d]*A[d,n]) + xc[d]*delta[d]*sum_n Bm[n]^2
__global__ __launch_bounds__(512) void ssm_combine_k(
        const float* __restrict__ xc, const float* __restrict__ delta,
        const float* __restrict__ Bm, const float* __restrict__ A,
        const float* __restrict__ res, float* __restrict__ comb) {
    int row = blockIdx.x;             // 0..511
    int d = threadIdx.x;              // 0..511
    __shared__ float bx[S_], bm[S_];
    __shared__ float s2[2];
    if (d < S_)          bx[d]       = Bm[(size_t)row * S_ + d];
    else if (d < 2 * S_) bm[d - S_]  = Bm[(size_t)(512 + row) * S_ + (d - S_)];
    __syncthreads();
    if (d < 64) {
        float p = bx[d] * bx[d] + bx[d + 64] * bx[d + 64];
        for (int off = 32; off; off >>= 1) p += __shfl_xor(p, off);
        if (d == 0) s2[0] = p;
    } else if (d < 128) {
        int l = d - 64;
        float p = bm[l] * bm[l] + bm[l + 64] * bm[l + 64];
        for (int off = 32; off; off >>= 1) p += __shfl_xor(p, off);
        if (l == 0) s2[1] = p;
    }
    __syncthreads();
    float dx = delta[(size_t)row * D2_ + d];
    float dm = delta[(size_t)(512 + row) * D2_ + d];
    float xx = xc[(size_t)row * D2_ + d];
    float xm = xc[(size_t)(512 + row) * D2_ + d];
    const float* Ad = A + (size_t)d * S_;
    float accx = 0.f, accm = 0.f;
    for (int n = 0; n < S_; n += 4) {
        float4 a4 = *reinterpret_cast<const float4*>(Ad + n);
        accx += bx[n]     * __expf(dx * a4.x);
        accx += bx[n + 1] * __expf(dx * a4.y);
        accx += bx[n + 2] * __expf(dx * a4.z);
        accx += bx[n + 3] * __expf(dx * a4.w);
        accm += bm[n]     * __expf(dm * a4.x);
        accm += bm[n + 1] * __expf(dm * a4.y);
        accm += bm[n + 2] * __expf(dm * a4.z);
        accm += bm[n + 3] * __expf(dm * a4.w);
    }
    float sx = accx + xx * dx * s2[0];
    float sm = accm + xm * dm * s2[1];
    comb[(size_t)row * D2_ + d] = (silu_f(sx) + silu_f(sm)) * res[(size_t)row * D2_ + d];
}

extern "C" void kernel_launch(void* const* d_in, const int* in_sizes, int n_in,
                              void* d_out, int out_size, void* d_ws, size_t ws_size,
                              hipStream_t stream) {
    const float* x      = (const float*)d_in[0];
    const float* mouth  = (const float*)d_in[1];
    const float* norm_w = (const float*)d_in[2];
    const float* inp_W  = (const float*)d_in[3];
    const float* inp_b  = (const float*)d_in[4];
    const float* out_W  = (const float*)d_in[5];
    const float* out_b  = (const float*)d_in[6];
    const float* Dlin_W = (const float*)d_in[7];
    const float* Dlin_b = (const float*)d_in[8];
    const float* conv_W = (const float*)d_in[9];
    const float* conv_b = (const float*)d_in[10];
    const float* fc1_W  = (const float*)d_in[11];
    const float* fc1_b  = (const float*)d_in[12];
    const float* fc2_W  = (const float*)d_in[13];
    const float* fc2_b  = (const float*)d_in[14];
    const float* A      = (const float*)d_in[15];

    float* ws    = (float*)d_ws;
    float* invr  = ws;                        // 1024
    float* xp    = invr + 1024;               // 1024*512
    float* xc    = xp + 1024 * 512;           // 1024*512
    float* res   = xc + 1024 * 512;           // 512*512
    float* Bmb   = res + 512 * 512;           // 1024*128
    float* comb  = Bmb + 1024 * 128;          // 512*512
    float* delta = xp;                        // alias: xp dead after conv
    float* out   = (float*)d_out;

    // 1) per-row inverse RMS for x (0..511) and mouth (512..1023)
    invrms_k<<<256, 256, 0, stream>>>(x, mouth, invr);
    // 2) fused-norm dual GEMM: xp = xn@inp_W^T+b (1024x512 -> 256 blocks),
    //    res = silu(xn_x@Dlin_W^T+b) (512x512 -> 128 blocks); total 384.
    gemm_dual_k<true, 0, 1><<<384, 256, 0, stream>>>(
        x, mouth, norm_w, invr,
        inp_W, inp_b, xp, 8, 512, 256,
        Dlin_W, Dlin_b, res, 8, 512, 256);
    // 3) xc = silu(conv3x3(xp) + cb)
    conv_silu_k<<<2048, 256, 0, stream>>>(xp, conv_W, conv_b, xc);
    // 4) dual GEMM: delta = softplus(xc@fc1_W^T+b) (1024x512 -> 256 blocks),
    //    Bm = xc@fc2_W^T+b (1024x128 -> 64 blocks); total 320.
    gemm_dual_k<false, 2, 0><<<320, 256, 0, stream>>>(
        xc, xc + (size_t)512 * 512, nullptr, nullptr,
        fc1_W, fc1_b, delta, 8, 512, 256,
        fc2_W, fc2_b, Bmb, 2, 128, 512);
    // 5) comb = (silu(ssm_x) + silu(ssm_m)) * res  (512x512)
    ssm_combine_k<<<512, 512, 0, stream>>>(xc, delta, Bmb, A, res, comb);
    // 6) out = comb @ out_W^T + out_b  (512x256, K=512 -> 64 blocks)
    gemm_dual_k<false, 0, 0><<<64, 256, 0, stream>>>(
        comb, comb, nullptr, nullptr,
        out_W, out_b, out, 4, 256, 64,
        nullptr, nullptr, nullptr, 1, 1, 512);
}